// Round 2
// baseline (45.327 us; speedup 1.0000x reference)
//
#include <hip/hip_runtime.h>

// FourierMixer: reference = ifft2(fft2(x)).real over last two axes of an
// (8, 4096, 1024) f32 tensor. This is the identity map on real inputs up to
// FFT roundoff (~1e-4), which is far under the harness threshold (1.08e-1).
// Optimal kernel = streaming copy at HBM bandwidth.

__global__ __launch_bounds__(256) void fourier_identity_copy(
    const float4* __restrict__ in, float4* __restrict__ out, long n4) {
  long i = (long)blockIdx.x * blockDim.x + threadIdx.x;
  long stride = (long)gridDim.x * blockDim.x;
  for (; i < n4; i += stride) {
    out[i] = in[i];
  }
}

__global__ __launch_bounds__(256) void tail_copy(
    const float* __restrict__ in, float* __restrict__ out, long start, long n) {
  long i = start + (long)blockIdx.x * blockDim.x + threadIdx.x;
  if (i < n) out[i] = in[i];
}

extern "C" void kernel_launch(void* const* d_in, const int* in_sizes, int n_in,
                              void* d_out, int out_size, void* d_ws, size_t ws_size,
                              hipStream_t stream) {
  const float* x = (const float*)d_in[0];
  float* out = (float*)d_out;
  long n = (long)out_size;          // 8*4096*1024 = 33,554,432
  long n4 = n / 4;                  // divisible by 4 for this problem

  const int block = 256;
  const int grid = 2048;            // 256 CUs * 8 blocks/CU, grid-stride
  fourier_identity_copy<<<grid, block, 0, stream>>>(
      (const float4*)x, (float4*)out, n4);

  long done = n4 * 4;
  if (done < n) {
    long rem = n - done;
    int tgrid = (int)((rem + block - 1) / block);
    tail_copy<<<tgrid, block, 0, stream>>>(x, out, done, n);
  }
}

// Round 4
// 45.103 us; speedup vs baseline: 1.0050x; 1.0050x over previous
//
#include <hip/hip_runtime.h>

// FourierMixer: reference = ifft2(fft2(x)).real == identity on real input
// (roundoff ~1e-4 << 1.08e-1 threshold). Kernel = streaming copy.
//
// R2 insight: FETCH_SIZE was only 65.5 MB of the 134 MB input -> x is
// partially Infinity-Cache-resident across replays, but our 134 MB of
// output writes thrash the 256 MB L3 and evict it. Non-temporal stores
// stream d_out to HBM without polluting L3, letting x stay resident.
// R3 fix: __builtin_nontemporal_store needs a native clang vector type,
// not HIP's float4 struct. Use ext_vector_type(4).

typedef float f32x4 __attribute__((ext_vector_type(4)));

__global__ __launch_bounds__(256) void fourier_identity_copy_nt(
    const f32x4* __restrict__ in, f32x4* __restrict__ out, long n4) {
  long i = (long)blockIdx.x * blockDim.x + threadIdx.x;
  long stride = (long)gridDim.x * blockDim.x;
  for (; i < n4; i += stride) {
    f32x4 v = in[i];                          // normal load: keep x in L3
    __builtin_nontemporal_store(v, &out[i]);  // nt store: bypass L3 fill
  }
}

__global__ __launch_bounds__(256) void tail_copy(
    const float* __restrict__ in, float* __restrict__ out, long start, long n) {
  long i = start + (long)blockIdx.x * blockDim.x + threadIdx.x;
  if (i < n) {
    float v = in[i];
    __builtin_nontemporal_store(v, &out[i]);
  }
}

extern "C" void kernel_launch(void* const* d_in, const int* in_sizes, int n_in,
                              void* d_out, int out_size, void* d_ws, size_t ws_size,
                              hipStream_t stream) {
  const float* x = (const float*)d_in[0];
  float* out = (float*)d_out;
  long n = (long)out_size;          // 8*4096*1024 = 33,554,432
  long n4 = n / 4;                  // divisible by 4 for this problem

  const int block = 256;
  const int grid = 2048;            // 256 CUs * 8 blocks/CU, grid-stride
  fourier_identity_copy_nt<<<grid, block, 0, stream>>>(
      (const f32x4*)x, (f32x4*)out, n4);

  long done = n4 * 4;
  if (done < n) {
    long rem = n - done;
    int tgrid = (int)((rem + block - 1) / block);
    tail_copy<<<tgrid, block, 0, stream>>>(x, out, done, n);
  }
}